// Round 12
// baseline (435.455 us; speedup 1.0000x reference)
//
#include <hip/hip_runtime.h>
#include <math.h>

#define N_NODES 100000
#define N_EDGES 1000000
#define F 128
#define NC 40
#define BN_EPS 1e-5f
#define CH 64
#define EC (N_EDGES / CH)      // 15625
#define WIN0 65536
#define NB1 (N_NODES - WIN0)   // 34464
#define PROW (N_NODES / 4)     // 25000 u32 words per partial row
#define WIN8 12500             // csr-fill window (8 windows exactly)
#define W8W (WIN8 / 4)         // 3125 words
#define CSU 68                 // LDS C-tile row stride in uints (64 data + 4 pad)
#define GB 1563                // gemm blocks = ceil(N_NODES/64)
#define X2S 32                 // x2bf row stride in uints (128 B aligned)

typedef unsigned int uint;
typedef unsigned short ushort;
typedef __attribute__((ext_vector_type(8))) short vbf8;
typedef __attribute__((ext_vector_type(4))) float vf4;

__device__ __forceinline__ float bf_lo(uint v) { return __uint_as_float(v << 16); }
__device__ __forceinline__ float bf_hi(uint v) { return __uint_as_float(v & 0xffff0000u); }
__device__ __forceinline__ ushort f2bf(float f) {
  uint u = __float_as_uint(f);
  u = u + 0x7fffu + ((u >> 16) & 1u);
  return (ushort)(u >> 16);
}
__device__ __forceinline__ uint pk2(float a, float b) {
  return (uint)f2bf(a) | ((uint)f2bf(b) << 16);
}

// ---------------- LDS byte-histogram counting (two windows, 64 KB LDS, CH=64 chunks) ----------------
__global__ __launch_bounds__(256) void hist_count_k(
    const int* __restrict__ s0, const int* __restrict__ d0,
    const int* __restrict__ s1, const int* __restrict__ d1,
    unsigned* __restrict__ partial) {
  __shared__ unsigned bins[16384];
  int c = blockIdx.x, w = blockIdx.y, a = blockIdx.z;
  const int* keys = (a == 0) ? s0 : (a == 1) ? d0 : (a == 2) ? s1 : d1;
  int base = w * WIN0;
  int nb = w ? NB1 : WIN0;
  int nwords = nb >> 2;
  int t = threadIdx.x;
  for (int i = t; i < nwords; i += 256) bins[i] = 0;
  __syncthreads();
  int e0 = c * EC;
  for (int e = e0 + t; e < e0 + EC; e += 256) {
    int b = keys[e] - base;
    if ((unsigned)b < (unsigned)nb)
      atomicAdd(&bins[b >> 2], 1u << ((b & 3) * 8));
  }
  __syncthreads();
  unsigned* dst = partial + (size_t)(a * CH + c) * PROW + (w ? (WIN0 >> 2) : 0);
  for (int i = t; i < nwords; i += 256) dst[i] = bins[i];
}

// sum partials -> rsqrt-degrees; overwrite din rows with chunk prefixes.
__global__ __launch_bounds__(256) void deg_reduce_k(
    unsigned* __restrict__ partial, float* __restrict__ rs4, ushort* __restrict__ rsO01u,
    int* __restrict__ degIn0, int* __restrict__ degIn1) {
  int word = blockIdx.x * 256 + threadIdx.x;
  if (word >= PROW) return;
  int a = blockIdx.y;
  bool din = (a == 1) || (a == 3);
  unsigned r0 = 0, r1 = 0, r2 = 0, r3 = 0;
  unsigned* rowp = partial + (size_t)a * CH * PROW + word;
  for (int c = 0; c < CH; ++c) {
    unsigned* p = rowp + (size_t)c * PROW;
    unsigned v = *p;
    if (din) *p = r0 | (r1 << 8) | (r2 << 16) | (r3 << 24);
    r0 += v & 255u; r1 += (v >> 8) & 255u; r2 += (v >> 16) & 255u; r3 += (v >> 24) & 255u;
  }
  int b = word * 4;
  float4 r;
  r.x = rsqrtf((float)max(r0, 1u));
  r.y = rsqrtf((float)max(r1, 1u));
  r.z = rsqrtf((float)max(r2, 1u));
  r.w = rsqrtf((float)max(r3, 1u));
  *(float4*)&rs4[(size_t)a * N_NODES + b] = r;
  if (a == 0) {
    rsO01u[2 * (b + 0)] = f2bf(r.x); rsO01u[2 * (b + 1)] = f2bf(r.y);
    rsO01u[2 * (b + 2)] = f2bf(r.z); rsO01u[2 * (b + 3)] = f2bf(r.w);
  }
  if (a == 2) {
    rsO01u[2 * (b + 0) + 1] = f2bf(r.x); rsO01u[2 * (b + 1) + 1] = f2bf(r.y);
    rsO01u[2 * (b + 2) + 1] = f2bf(r.z); rsO01u[2 * (b + 3) + 1] = f2bf(r.w);
  }
  if (a == 1) { degIn0[b] = r0; degIn0[b + 1] = r1; degIn0[b + 2] = r2; degIn0[b + 3] = r3; }
  if (a == 3) { degIn1[b] = r0; degIn1[b + 1] = r1; degIn1[b + 2] = r2; degIn1[b + 3] = r3; }
}

// ---------------- 2-level exclusive scan (both graphs via blockIdx.y) ----------------
__global__ void scan_local_k(const int* __restrict__ cnt0, const int* __restrict__ cnt1,
                             int* __restrict__ out0, int* __restrict__ out1,
                             int* __restrict__ bsum) {
  __shared__ int lds[256];
  const int* cnt = blockIdx.y ? cnt1 : cnt0;
  int* out = blockIdx.y ? out1 : out0;
  int base = blockIdx.x * 2048;
  int t = threadIdx.x;
  int v[8];
  int s = 0;
#pragma unroll
  for (int j = 0; j < 8; ++j) {
    int idx = base + t * 8 + j;
    v[j] = (idx < N_NODES) ? cnt[idx] : 0;
    s += v[j];
  }
  lds[t] = s;
  __syncthreads();
  for (int off = 1; off < 256; off <<= 1) {
    int x = (t >= off) ? lds[t - off] : 0;
    __syncthreads();
    lds[t] += x;
    __syncthreads();
  }
  int excl = lds[t] - s;
  if (t == 255) bsum[blockIdx.y * 64 + blockIdx.x] = lds[255];
  int run = excl;
#pragma unroll
  for (int j = 0; j < 8; ++j) {
    int idx = base + t * 8 + j;
    if (idx < N_NODES) out[idx] = run;
    run += v[j];
  }
}

// apply block offsets; top-scan of raw block sums done in-kernel (wave 0)
__global__ void scan_apply_k(int* __restrict__ rp0, int* __restrict__ rp1,
                             const int* __restrict__ bsum) {
  __shared__ int ps[64];
  int* rp = blockIdx.y ? rp1 : rp0;
  const int* bs = bsum + blockIdx.y * 64;
  int t = threadIdx.x;
  if (t < 64) {
    int orig = bs[t];
    int v = orig;
#pragma unroll
    for (int off = 1; off < 64; off <<= 1) {
      int u = __shfl_up(v, off);
      if (t >= off) v += u;
    }
    ps[t] = v - orig;   // exclusive prefix
  }
  __syncthreads();
  int i = blockIdx.x * 256 + t;
  if (i < N_NODES) rp[i] += ps[i >> 11];
  if (i == 0) rp[N_NODES] = N_EDGES;
}

// ---------------- atomic-free CSR fill: 8 XCD-pinned windows (write locality) ----------------
// Grid dim3(8, CH, 2): blockIdx.x = window = XCD (flattened wgid%8). Window = 12500 nodes;
// per-window csr output region ~1 MB/graph stays L2-resident on its XCD -> writes coalesce.
__global__ __launch_bounds__(256) void csr_fill8_k(
    const int* __restrict__ src0, const int* __restrict__ dst0, const int* __restrict__ rp0g,
    int* __restrict__ csr0g,
    const int* __restrict__ src1, const int* __restrict__ dst1, const int* __restrict__ rp1g,
    int* __restrict__ csr1g, const unsigned* __restrict__ partial) {
  __shared__ unsigned bins[W8W];   // 12.5 KB
  int w = blockIdx.x, c = blockIdx.y, g = blockIdx.z;
  const int* src = g ? src1 : src0;
  const int* dst = g ? dst1 : dst0;
  const int* rp = g ? rp1g : rp0g;
  int* csr = g ? csr1g : csr0g;
  int aIdx = g ? 3 : 1;
  int base = w * WIN8;
  const unsigned* sp = partial + (size_t)(aIdx * CH + c) * PROW + (base >> 2);
  int t = threadIdx.x;
  for (int i = t; i < W8W; i += 256) bins[i] = sp[i];
  __syncthreads();
  int e0 = c * EC;
  for (int e = e0 + t; e < e0 + EC; e += 256) {
    int d = dst[e];
    int b = d - base;
    if ((unsigned)b < (unsigned)WIN8) {
      int sh = (b & 3) * 8;
      unsigned old = atomicAdd(&bins[b >> 2], 1u << sh);
      int off = (old >> sh) & 255;
      csr[rp[d] + off] = src[e];
    }
  }
}

// ---------------- pack: feat fp32 -> bf16 rows (blocks 0..1023) + weights (blocks 1024..1055) ----------------
__global__ __launch_bounds__(256) void pack_all_k(
    const float* __restrict__ x, uint* __restrict__ y,
    const float* __restrict__ Wa, const float* __restrict__ Wb,
    const float* __restrict__ Wc, const float* __restrict__ Wd,
    ushort* __restrict__ pk) {
  int b = blockIdx.x;
  int t = threadIdx.x;
  if (b < 1024) {
    size_t total = (size_t)N_NODES * F / 8;
    for (size_t idx = b * 256 + t; idx < total; idx += (size_t)1024 * 256) {
      float4 v1 = ((const float4*)x)[idx * 2];
      float4 v2 = ((const float4*)x)[idx * 2 + 1];
      uint4 o;
      o.x = pk2(v1.x, v1.y);
      o.y = pk2(v1.z, v1.w);
      o.z = pk2(v2.x, v2.y);
      o.w = pk2(v2.z, v2.w);
      ((uint4*)y)[idx] = o;
    }
  } else {
    int bb = b - 1024;              // 0..31
    int m = bb >> 3;                // weight matrix 0..3
    int idx = (bb & 7) * 256 + t;   // 0..2047 = ks*512 + nt*64 + lane
    const float* W = (m == 0) ? Wa : (m == 1) ? Wb : (m == 2) ? Wc : Wd;
    int lane = idx & 63;
    int nt = (idx >> 6) & 7;
    int ks = idx >> 9;
    int j = (lane & 15) + nt * 16;
    int kb = (lane >> 4) * 8 + ks * 32;
    ushort v[8];
#pragma unroll
    for (int q = 0; q < 8; ++q) v[q] = f2bf(W[(size_t)(kb + q) * F + j]);
    *(uint4*)(pk + (size_t)m * 16384 + (size_t)idx * 8) = *(uint4*)v;
  }
}

// ---------------- stat reduction: GB per-block partials -> 64 -> 1 (no atomics) ----------------
__global__ void st_part_k(const float* __restrict__ stm, float* __restrict__ stp, int ncopies) {
  int b = blockIdx.x, t = threadIdx.x;
  int lo = b * 25, hi = min(ncopies, lo + 25);
  float s = 0.f;
  for (int k = lo; k < hi; ++k) s += stm[(size_t)k * 256 + t];
  stp[b * 256 + t] = s;
}

__global__ void st_final_k(const float* __restrict__ stp, float* __restrict__ st) {
  int t = threadIdx.x;
  float s = 0.f;
#pragma unroll
  for (int k = 0; k < 64; ++k) s += stp[k * 256 + t];
  st[t] = s;
}

// ---------------- quarter-wave gather helpers ----------------
__device__ __forceinline__ void acc8(uint4 v, float c, float* a) {
  a[0] = fmaf(bf_lo(v.x), c, a[0]); a[1] = fmaf(bf_hi(v.x), c, a[1]);
  a[2] = fmaf(bf_lo(v.y), c, a[2]); a[3] = fmaf(bf_hi(v.y), c, a[3]);
  a[4] = fmaf(bf_lo(v.z), c, a[4]); a[5] = fmaf(bf_hi(v.z), c, a[5]);
  a[6] = fmaf(bf_lo(v.w), c, a[6]); a[7] = fmaf(bf_hi(v.w), c, a[7]);
}

__device__ __forceinline__ void gather_run(const int* __restrict__ p, int n, float w,
                                           const float* __restrict__ rsO,
                                           const uint4* __restrict__ xr, int l, float* a) {
  int e = 0;
  for (; e + 3 < n; e += 4) {
    int s0 = p[e], s1 = p[e + 1], s2 = p[e + 2], s3 = p[e + 3];
    float c0 = w * rsO[s0], c1 = w * rsO[s1];
    float c2 = w * rsO[s2], c3 = w * rsO[s3];
    uint4 v0 = xr[(size_t)s0 * 16 + l];
    uint4 v1 = xr[(size_t)s1 * 16 + l];
    uint4 v2 = xr[(size_t)s2 * 16 + l];
    uint4 v3 = xr[(size_t)s3 * 16 + l];
    acc8(v0, c0, a); acc8(v1, c1, a); acc8(v2, c2, a); acc8(v3, c3, a);
  }
  for (; e < n; ++e) {
    int s = p[e];
    float c = w * rsO[s];
    uint4 v = xr[(size_t)s * 16 + l];
    acc8(v, c, a);
  }
}

// ---------------- dual-graph gather, 16-lane groups (uint4/lane), split per-graph loops ----------------
__global__ __launch_bounds__(256) void gather_dual_q_k(
    const uint* __restrict__ xbf, const float* __restrict__ attn,
    const float* __restrict__ rsO0f, const float* __restrict__ rsO1f,
    const float* __restrict__ rsI0, const int* __restrict__ rp0, const int* __restrict__ csr0,
    const float* __restrict__ rsI1, const int* __restrict__ rp1, const int* __restrict__ csr1,
    uint* __restrict__ outbf) {
  int node = blockIdx.x * 16 + (threadIdx.x >> 4);
  int l = threadIdx.x & 15;
  int b0 = rp0[node], n0 = rp0[node + 1] - b0;
  int b1 = rp1[node], n1 = rp1[node + 1] - b1;
  float w0 = attn[0] * rsI0[node];
  float w1 = attn[1] * rsI1[node];
  const uint4* xr = (const uint4*)xbf;
  float a[8] = {0.f, 0.f, 0.f, 0.f, 0.f, 0.f, 0.f, 0.f};
  gather_run(csr0 + b0, n0, w0, rsO0f, xr, l, a);
  gather_run(csr1 + b1, n1, w1, rsO1f, xr, l, a);
  uint4 o;
  o.x = pk2(a[0], a[1]); o.y = pk2(a[2], a[3]);
  o.z = pk2(a[4], a[5]); o.w = pk2(a[6], a[7]);
  ((uint4*)outbf)[(size_t)node * 16 + l] = o;
}

// ---------------- single-graph gather + inline BN/ReLU on sources, 16-lane groups ----------------
__device__ __forceinline__ void accbn(uint4 v, float c, const float* sc, const float* sh,
                                      float* a) {
  a[0] = fmaf(fmaxf(fmaf(bf_lo(v.x), sc[0], sh[0]), 0.f), c, a[0]);
  a[1] = fmaf(fmaxf(fmaf(bf_hi(v.x), sc[1], sh[1]), 0.f), c, a[1]);
  a[2] = fmaf(fmaxf(fmaf(bf_lo(v.y), sc[2], sh[2]), 0.f), c, a[2]);
  a[3] = fmaf(fmaxf(fmaf(bf_hi(v.y), sc[3], sh[3]), 0.f), c, a[3]);
  a[4] = fmaf(fmaxf(fmaf(bf_lo(v.z), sc[4], sh[4]), 0.f), c, a[4]);
  a[5] = fmaf(fmaxf(fmaf(bf_hi(v.z), sc[5], sh[5]), 0.f), c, a[5]);
  a[6] = fmaf(fmaxf(fmaf(bf_lo(v.w), sc[6], sh[6]), 0.f), c, a[6]);
  a[7] = fmaf(fmaxf(fmaf(bf_hi(v.w), sc[7], sh[7]), 0.f), c, a[7]);
}

__global__ __launch_bounds__(256) void gather_bn_q_k(
    const uint* __restrict__ xbf, const float* __restrict__ st,
    const float* __restrict__ gamma, const float* __restrict__ beta,
    const float* __restrict__ rsO,
    const float* __restrict__ rsI, const int* __restrict__ rp, const int* __restrict__ csr,
    uint* __restrict__ outbf) {
  int node = blockIdx.x * 16 + (threadIdx.x >> 4);
  int l = threadIdx.x & 15;
  float sc[8], sh[8];
#pragma unroll
  for (int j = 0; j < 8; ++j) {
    int c = 8 * l + j;
    float m = st[c] * (1.f / (float)N_NODES);
    float v = st[128 + c] * (1.f / (float)N_NODES) - m * m;
    float s = gamma[c] * rsqrtf(fmaxf(v, 0.f) + BN_EPS);
    sc[j] = s;
    sh[j] = beta[c] - m * s;
  }
  int b0 = rp[node], T = rp[node + 1] - b0;
  const int* p = csr + b0;
  const uint4* xr = (const uint4*)xbf;
  float a[8] = {0.f, 0.f, 0.f, 0.f, 0.f, 0.f, 0.f, 0.f};
  int e = 0;
  for (; e + 1 < T; e += 2) {
    int s0 = p[e], s1 = p[e + 1];
    float c0 = rsO[s0], c1 = rsO[s1];
    uint4 v0 = xr[(size_t)s0 * 16 + l];
    uint4 v1 = xr[(size_t)s1 * 16 + l];
    accbn(v0, c0, sc, sh, a);
    accbn(v1, c1, sc, sh, a);
  }
  if (e < T) {
    int s0 = p[e];
    float c0 = rsO[s0];
    uint4 v0 = xr[(size_t)s0 * 16 + l];
    accbn(v0, c0, sc, sh, a);
  }
  float sd = rsI[node];
  uint4 o;
  o.x = pk2(a[0] * sd, a[1] * sd); o.y = pk2(a[2] * sd, a[3] * sd);
  o.z = pk2(a[4] * sd, a[5] * sd); o.w = pk2(a[6] * sd, a[7] * sd);
  ((uint4*)outbf)[(size_t)node * 16 + l] = o;
}

// ---------------- gather 40 cols (bf16 input, 128B-aligned rows), accumulate into out ----------------
__global__ void gather40_add_k(const uint* __restrict__ x2bf, const float* __restrict__ rsI,
                               const int* __restrict__ rp, const int* __restrict__ csr,
                               float* __restrict__ out) {
  int node = (blockIdx.x * 256 + threadIdx.x) >> 5;
  int lane = threadIdx.x & 31;
  if (node >= N_NODES || lane >= 20) return;
  float l = 0.f, h = 0.f;
  int e = rp[node], end = rp[node + 1];
  for (; e + 3 < end; e += 4) {
    int sA = csr[e], sB = csr[e + 1], sC = csr[e + 2], sD = csr[e + 3];
    uint vA = x2bf[(size_t)sA * X2S + lane];
    uint vB = x2bf[(size_t)sB * X2S + lane];
    uint vC = x2bf[(size_t)sC * X2S + lane];
    uint vD = x2bf[(size_t)sD * X2S + lane];
    l += (bf_lo(vA) + bf_lo(vB)) + (bf_lo(vC) + bf_lo(vD));
    h += (bf_hi(vA) + bf_hi(vB)) + (bf_hi(vC) + bf_hi(vD));
  }
  for (; e < end; ++e) {
    uint vA = x2bf[(size_t)csr[e] * X2S + lane];
    l += bf_lo(vA);
    h += bf_hi(vA);
  }
  float sd = rsI[node];
  float2 p = *(float2*)(out + (size_t)node * NC + lane * 2);
  *(float2*)(out + (size_t)node * NC + lane * 2) = make_float2(p.x + l * sd, p.y + h * sd);
}

// ---------------- MFMA dual GEMM: direct A loads, LDS C epilogue, no global atomics ----------------
__global__ __launch_bounds__(256) void gemm_mfma_k(
    const ushort* __restrict__ A1, const ushort* __restrict__ A2,
    const ushort* __restrict__ pkA, const ushort* __restrict__ pkB,
    float* __restrict__ stm, ushort* __restrict__ Cb) {
  __shared__ uint Cl[64 * CSU];   // 17.4 KB
  __shared__ float sst[256];
  int t = threadIdx.x;
  sst[t] = 0.f;
  __syncthreads();
  int wave = t >> 6, lane = t & 63;
  int kgrp = lane >> 4, lrow = lane & 15;
  int arow = blockIdx.x * 64 + wave * 16 + lrow;
  bool rok = arow < N_NODES;
  const vbf8* a1p = (const vbf8*)(A1 + (size_t)(rok ? arow : 0) * F);
  const vbf8* a2p = (const vbf8*)(A2 + (size_t)(rok ? arow : 0) * F);
  const vbf8* wap = (const vbf8*)pkA + lane;
  const vbf8* wbp = (const vbf8*)pkB + lane;
  vbf8 zero = {0, 0, 0, 0, 0, 0, 0, 0};
  vf4 acc[8];
#pragma unroll
  for (int i = 0; i < 8; ++i) acc[i] = (vf4){0.f, 0.f, 0.f, 0.f};
#pragma unroll
  for (int ks = 0; ks < 4; ++ks) {
    vbf8 a1 = rok ? a1p[ks * 4 + kgrp] : zero;
    vbf8 a2 = rok ? a2p[ks * 4 + kgrp] : zero;
#pragma unroll
    for (int nt = 0; nt < 8; ++nt)
      acc[nt] = __builtin_amdgcn_mfma_f32_16x16x32_bf16(a1, wap[(ks * 8 + nt) * 64], acc[nt], 0, 0, 0);
#pragma unroll
    for (int nt = 0; nt < 8; ++nt)
      acc[nt] = __builtin_amdgcn_mfma_f32_16x16x32_bf16(a2, wbp[(ks * 8 + nt) * 64], acc[nt], 0, 0, 0);
  }
  // epilogue: pair-pack C into LDS, block-wide stats into LDS
  int row_l = wave * 16 + kgrp * 4;
#pragma unroll
  for (int nt = 0; nt < 8; ++nt) {
#pragma unroll
    for (int r = 0; r < 4; ++r) {
      float w = acc[nt][r];
      float o = __shfl_xor(w, 1);
      if ((lrow & 1) == 0) Cl[(row_l + r) * CSU + nt * 8 + (lrow >> 1)] = pk2(w, o);
    }
  }
#pragma unroll
  for (int nt = 0; nt < 8; ++nt) {
    float s = acc[nt][0] + acc[nt][1] + acc[nt][2] + acc[nt][3];
    float q = acc[nt][0] * acc[nt][0] + acc[nt][1] * acc[nt][1] +
              acc[nt][2] * acc[nt][2] + acc[nt][3] * acc[nt][3];
    s += __shfl_xor(s, 16); q += __shfl_xor(q, 16);
    s += __shfl_xor(s, 32); q += __shfl_xor(q, 32);
    if (lane < 16) {
      atomicAdd(&sst[nt * 16 + lane], s);
      atomicAdd(&sst[128 + nt * 16 + lane], q);
    }
  }
  __syncthreads();
  // coalesced C store: 64 rows x 64 uints = 1024 uint4
#pragma unroll
  for (int i = 0; i < 4; ++i) {
    int u = t + 256 * i;
    int row = u >> 4, seg = (u & 15) * 4;
    int grow = blockIdx.x * 64 + row;
    if (grow < N_NODES)
      *(uint4*)((uint*)Cb + (size_t)grow * 64 + seg) = *(uint4*)&Cl[row * CSU + seg];
  }
  // per-block stat partials: plain coalesced store (no device atomics)
  stm[(size_t)blockIdx.x * 256 + t] = sst[t];
}

// ---------------- MFMA dual GEMM, A2 = relu(bn(raw)) at fragment load (in-place safe) ----------------
__global__ __launch_bounds__(256) void gemm_mfma_bn_k(
    const ushort* __restrict__ A1, const ushort* __restrict__ A2,
    const float* __restrict__ stin, const float* __restrict__ gamma,
    const float* __restrict__ beta,
    const ushort* __restrict__ pkA, const ushort* __restrict__ pkB,
    float* __restrict__ stm, ushort* __restrict__ Cb) {
  __shared__ uint Cl[64 * CSU];
  __shared__ float sst[256];
  __shared__ float scl[128], shl[128];
  int t = threadIdx.x;
  sst[t] = 0.f;
  if (t < 128) {
    float m = stin[t] * (1.f / (float)N_NODES);
    float v = stin[128 + t] * (1.f / (float)N_NODES) - m * m;
    float s = gamma[t] * rsqrtf(fmaxf(v, 0.f) + BN_EPS);
    scl[t] = s;
    shl[t] = beta[t] - m * s;
  }
  __syncthreads();
  int wave = t >> 6, lane = t & 63;
  int kgrp = lane >> 4, lrow = lane & 15;
  int arow = blockIdx.x * 64 + wave * 16 + lrow;
  bool rok = arow < N_NODES;
  const vbf8* a1p = (const vbf8*)(A1 + (size_t)(rok ? arow : 0) * F);
  const vbf8* a2p = (const vbf8*)(A2 + (size_t)(rok ? arow : 0) * F);
  const vbf8* wap = (const vbf8*)pkA + lane;
  const vbf8* wbp = (const vbf8*)pkB + lane;
  vbf8 zero = {0, 0, 0, 0, 0, 0, 0, 0};
  vf4 acc[8];
#pragma unroll
  for (int i = 0; i < 8; ++i) acc[i] = (vf4){0.f, 0.f, 0.f, 0.f};
#pragma unroll
  for (int ks = 0; ks < 4; ++ks) {
    vbf8 a1 = rok ? a1p[ks * 4 + kgrp] : zero;
    vbf8 a2 = zero;
    if (rok) {
      vbf8 a2r = a2p[ks * 4 + kgrp];
      const float* scp = &scl[ks * 32 + kgrp * 8];
      const float* shp = &shl[ks * 32 + kgrp * 8];
      ushort o[8];
#pragma unroll
      for (int q = 0; q < 8; ++q) {
        float f = __uint_as_float(((uint)(ushort)a2r[q]) << 16);
        f = fmaxf(fmaf(f, scp[q], shp[q]), 0.f);
        o[q] = f2bf(f);
      }
      a2 = *(vbf8*)o;
    }
#pragma unroll
    for (int nt = 0; nt < 8; ++nt)
      acc[nt] = __builtin_amdgcn_mfma_f32_16x16x32_bf16(a1, wap[(ks * 8 + nt) * 64], acc[nt], 0, 0, 0);
#pragma unroll
    for (int nt = 0; nt < 8; ++nt)
      acc[nt] = __builtin_amdgcn_mfma_f32_16x16x32_bf16(a2, wbp[(ks * 8 + nt) * 64], acc[nt], 0, 0, 0);
  }
  int row_l = wave * 16 + kgrp * 4;
#pragma unroll
  for (int nt = 0; nt < 8; ++nt) {
#pragma unroll
    for (int r = 0; r < 4; ++r) {
      float w = acc[nt][r];
      float o = __shfl_xor(w, 1);
      if ((lrow & 1) == 0) Cl[(row_l + r) * CSU + nt * 8 + (lrow >> 1)] = pk2(w, o);
    }
  }
#pragma unroll
  for (int nt = 0; nt < 8; ++nt) {
    float s = acc[nt][0] + acc[nt][1] + acc[nt][2] + acc[nt][3];
    float q = acc[nt][0] * acc[nt][0] + acc[nt][1] * acc[nt][1] +
              acc[nt][2] * acc[nt][2] + acc[nt][3] * acc[nt][3];
    s += __shfl_xor(s, 16); q += __shfl_xor(q, 16);
    s += __shfl_xor(s, 32); q += __shfl_xor(q, 32);
    if (lane < 16) {
      atomicAdd(&sst[nt * 16 + lane], s);
      atomicAdd(&sst[128 + nt * 16 + lane], q);
    }
  }
  __syncthreads();   // all A2 reads complete before any store (in-place safe)
#pragma unroll
  for (int i = 0; i < 4; ++i) {
    int u = t + 256 * i;
    int row = u >> 4, seg = (u & 15) * 4;
    int grow = blockIdx.x * 64 + row;
    if (grow < N_NODES)
      *(uint4*)((uint*)Cb + (size_t)grow * 64 + seg) = *(uint4*)&Cl[row * CSU + seg];
  }
  stm[(size_t)blockIdx.x * 256 + t] = sst[t];
}

// ---------------- layer-2 dual GEMM (inline BN from raw stats) ----------------
__global__ __launch_bounds__(256) void gemm40_dual_k(
    const uint* __restrict__ h1b, const float* __restrict__ st,
    const float* __restrict__ gamma, const float* __restrict__ beta,
    const float* __restrict__ W2, const float* __restrict__ L2, const float* __restrict__ bias,
    const float* __restrict__ rsO, uint* __restrict__ x2bf, float* __restrict__ outp) {
  __shared__ float Alds[25 * 128];
  __shared__ float Wl[128 * NC];
  __shared__ float Ll[128 * NC];
  __shared__ float scl[128], shl[128];
  int t = threadIdx.x;
  int r0 = blockIdx.x * 25;
  if (t < 128) {
    float m = st[t] / (float)N_NODES;
    float v = st[128 + t] / (float)N_NODES - m * m;
    float s = gamma[t] * rsqrtf(fmaxf(v, 0.f) + BN_EPS);
    scl[t] = s;
    shl[t] = beta[t] - m * s;
  }
  __syncthreads();
#pragma unroll
  for (int p = 0; p < 4; ++p) {
    int flat = t * 4 + p * 1024;
    if (flat < 25 * 128) {
      int lrr = flat >> 7, k = flat & 127;
      int row = r0 + lrr;
      float4 v = make_float4(0.f, 0.f, 0.f, 0.f);
      if (row < N_NODES) {
        uint2 u = *(const uint2*)(h1b + (size_t)row * 64 + (k >> 1));
        v = make_float4(bf_lo(u.x), bf_hi(u.x), bf_lo(u.y), bf_hi(u.y));
      }
      float4 scv = *(float4*)&scl[k];
      float4 shv = *(float4*)&shl[k];
      v.x = fmaxf(fmaf(v.x, scv.x, shv.x), 0.f);
      v.y = fmaxf(fmaf(v.y, scv.y, shv.y), 0.f);
      v.z = fmaxf(fmaf(v.z, scv.z, shv.z), 0.f);
      v.w = fmaxf(fmaf(v.w, scv.w, shv.w), 0.f);
      *(float4*)&Alds[flat] = v;
    }
  }
#pragma unroll
  for (int p = 0; p < 5; ++p) {
    int flat = t * 4 + p * 1024;
    if (flat < 128 * NC) {
      *(float4*)&Wl[flat] = *(const float4*)(W2 + flat);
      *(float4*)&Ll[flat] = *(const float4*)(L2 + flat);
    }
  }
  __syncthreads();
  if (t < 250) {
    int lrr = t / 10, cg = t % 10;
    float w0 = 0.f, w1 = 0.f, w2 = 0.f, w3 = 0.f;
    float l0 = 0.f, l1 = 0.f, l2 = 0.f, l3 = 0.f;
#pragma unroll 8
    for (int k = 0; k < 128; ++k) {
      float a = Alds[lrr * 128 + k];
      float4 w = *(float4*)&Wl[k * NC + cg * 4];
      float4 l = *(float4*)&Ll[k * NC + cg * 4];
      w0 = fmaf(a, w.x, w0); w1 = fmaf(a, w.y, w1);
      w2 = fmaf(a, w.z, w2); w3 = fmaf(a, w.w, w3);
      l0 = fmaf(a, l.x, l0); l1 = fmaf(a, l.y, l1);
      l2 = fmaf(a, l.z, l2); l3 = fmaf(a, l.w, l3);
    }
    int row = r0 + lrr;
    if (row < N_NODES) {
      float s = rsO[row];
      uint2 xo = make_uint2(pk2(w0 * s, w1 * s), pk2(w2 * s, w3 * s));
      *(uint2*)(x2bf + (size_t)row * X2S + cg * 2) = xo;
      float4 bv = *(const float4*)(bias + cg * 4);
      float4 oo = make_float4(l0 + bv.x, l1 + bv.y, l2 + bv.z, l3 + bv.w);
      *(float4*)(outp + (size_t)row * NC + cg * 4) = oo;
    }
  }
}

extern "C" void kernel_launch(void* const* d_in, const int* in_sizes, int n_in,
                              void* d_out, int out_size, void* d_ws, size_t ws_size,
                              hipStream_t stream) {
  const float* feat = (const float*)d_in[0];
  const int* src0 = (const int*)d_in[1];
  const int* dst0 = (const int*)d_in[2];
  const int* src1 = (const int*)d_in[3];
  const int* dst1 = (const int*)d_in[4];
  const float* attn = (const float*)d_in[5];
  const float* W0 = (const float*)d_in[6];
  const float* W1 = (const float*)d_in[7];
  const float* W2 = (const float*)d_in[8];
  const float* b2 = (const float*)d_in[9];
  const float* L0 = (const float*)d_in[10];
  const float* L1 = (const float*)d_in[11];
  const float* L2 = (const float*)d_in[12];
  const float* gamma0 = (const float*)d_in[13];
  const float* beta0 = (const float*)d_in[14];
  const float* gamma1 = (const float*)d_in[15];
  const float* beta1 = (const float*)d_in[16];
  float* out = (float*)d_out;

  char* base = (char*)d_ws;
  size_t off = 0;
  auto alloc = [&](size_t bytes) -> void* {
    void* p = base + off;
    off += (bytes + 255) & ~(size_t)255;
    return p;
  };
  unsigned* partial = (unsigned*)alloc((size_t)4 * CH * PROW * 4);  // 25.6 MB
  float* rs4 = (float*)alloc(4 * (size_t)N_NODES * 4);
  uint* rsO01 = (uint*)alloc((size_t)N_NODES * 4);
  int* degIn0 = (int*)alloc(N_NODES * 4);
  int* degIn1 = (int*)alloc(N_NODES * 4);
  int* rp0 = (int*)alloc((N_NODES + 1) * 4);
  int* rp1 = (int*)alloc((N_NODES + 1) * 4);
  int* bsum = (int*)alloc(128 * 4);
  int* csr0 = (int*)alloc((size_t)N_EDGES * 4);
  int* csr1 = (int*)alloc((size_t)N_EDGES * 4);
  float* stm0 = (float*)alloc((size_t)GB * 256 * 4);       // 1.6 MB per-block stat partials
  float* stm1 = (float*)alloc((size_t)GB * 256 * 4);
  float* stp = (float*)alloc((size_t)64 * 256 * 4);        // 64 KB tree stage
  float* st0 = (float*)alloc(256 * 4);
  float* st1 = (float*)alloc(256 * 4);
  ushort* wpk = (ushort*)alloc((size_t)4 * 16384 * 2);     // 128 KB packed weights
  uint* featbf = (uint*)alloc((size_t)N_NODES * 64 * 4);   // 25.6 MB
  uint* aggbf = (uint*)alloc((size_t)N_NODES * 64 * 4);    // 25.6 MB
  uint* hrow = (uint*)alloc((size_t)N_NODES * 64 * 4);     // 25.6 MB (h0 then h1, bf16)
  uint* g1buf = (uint*)alloc((size_t)N_NODES * 64 * 4);    // 25.6 MB
  if (off > ws_size) return;

  // buffer reuse (sequential stream makes these safe)
  uint* x2bf = featbf;   // after gemm0 consumed featbf (needs 12.8 MB of its 25.6 MB)

  float* rs_out0 = rs4;                 // out-deg graph0 (fp32)
  float* rs_in0 = rs4 + N_NODES;        // in-deg graph0
  float* rs_out1 = rs4 + 2 * N_NODES;   // out-deg graph1
  float* rs_in1 = rs4 + 3 * N_NODES;    // in-deg graph1

  // graph prep
  hist_count_k<<<dim3(CH, 2, 4), 256, 0, stream>>>(src0, dst0, src1, dst1, partial);
  deg_reduce_k<<<dim3((PROW + 255) / 256, 4), 256, 0, stream>>>(
      partial, rs4, (ushort*)rsO01, degIn0, degIn1);
  const int SCB = (N_NODES + 2047) / 2048;
  scan_local_k<<<dim3(SCB, 2), 256, 0, stream>>>(degIn0, degIn1, rp0, rp1, bsum);
  scan_apply_k<<<dim3((N_NODES + 255) / 256, 2), 256, 0, stream>>>(rp0, rp1, bsum);
  // XCD-pinned 8-window CSR fill (write locality per window)
  csr_fill8_k<<<dim3(8, CH, 2), 256, 0, stream>>>(src0, dst0, rp0, csr0,
                                                  src1, dst1, rp1, csr1, partial);

  // packs (feat + weights in one launch)
  pack_all_k<<<1056, 256, 0, stream>>>(feat, featbf, W0, L0, W1, L1, wpk);

  // layer 0
  gather_dual_q_k<<<N_NODES / 16, 256, 0, stream>>>(featbf, attn, rs_out0, rs_out1,
                                                    rs_in0, rp0, csr0,
                                                    rs_in1, rp1, csr1, aggbf);
  gemm_mfma_k<<<GB, 256, 0, stream>>>((ushort*)aggbf, (ushort*)featbf, wpk, wpk + 16384,
                                      stm0, (ushort*)hrow);
  st_part_k<<<64, 256, 0, stream>>>(stm0, stp, GB);
  st_final_k<<<1, 256, 0, stream>>>(stp, st0);

  // layer 1 (BN+ReLU of h0 fused into gather and into gemm A2 path)
  gather_bn_q_k<<<N_NODES / 16, 256, 0, stream>>>(hrow, st0, gamma0, beta0, rs_out0,
                                                  rs_in0, rp0, csr0, g1buf);
  gemm_mfma_bn_k<<<GB, 256, 0, stream>>>((ushort*)g1buf, (ushort*)hrow, st0, gamma0, beta0,
                                         wpk + 2 * 16384, wpk + 3 * 16384, stm1, (ushort*)hrow);
  st_part_k<<<64, 256, 0, stream>>>(stm1, stp, GB);
  st_final_k<<<1, 256, 0, stream>>>(stp, st1);

  // layer 2
  gemm40_dual_k<<<(N_NODES + 24) / 25, 256, 0, stream>>>(hrow, st1, gamma1, beta1, W2, L2, b2,
                                                         rs_out0, x2bf, out);
  gather40_add_k<<<(N_NODES * 32 + 255) / 256, 256, 0, stream>>>(x2bf, rs_in0, rp0, csr0, out);
}

// Round 13
// 427.638 us; speedup vs baseline: 1.0183x; 1.0183x over previous
//
#include <hip/hip_runtime.h>
#include <math.h>

#define N_NODES 100000
#define N_EDGES 1000000
#define F 128
#define NC 40
#define BN_EPS 1e-5f
#define CH 64
#define EC (N_EDGES / CH)      // 15625
#define WIN0 65536
#define NB1 (N_NODES - WIN0)   // 34464
#define PROW (N_NODES / 4)     // 25000 u32 words per partial row
#define CSU 68                 // LDS C-tile row stride in uints (64 data + 4 pad)
#define GB 1563                // gemm blocks = ceil(N_NODES/64)
#define X2S 32                 // x2bf row stride in uints (128 B aligned)

typedef unsigned int uint;
typedef unsigned short ushort;
typedef __attribute__((ext_vector_type(8))) short vbf8;
typedef __attribute__((ext_vector_type(4))) float vf4;

__device__ __forceinline__ float bf_lo(uint v) { return __uint_as_float(v << 16); }
__device__ __forceinline__ float bf_hi(uint v) { return __uint_as_float(v & 0xffff0000u); }
__device__ __forceinline__ ushort f2bf(float f) {
  uint u = __float_as_uint(f);
  u = u + 0x7fffu + ((u >> 16) & 1u);
  return (ushort)(u >> 16);
}
__device__ __forceinline__ uint pk2(float a, float b) {
  return (uint)f2bf(a) | ((uint)f2bf(b) << 16);
}

// ---------------- LDS byte-histogram counting (two windows, 64 KB LDS, CH=64 chunks) ----------------
__global__ __launch_bounds__(256) void hist_count_k(
    const int* __restrict__ s0, const int* __restrict__ d0,
    const int* __restrict__ s1, const int* __restrict__ d1,
    unsigned* __restrict__ partial) {
  __shared__ unsigned bins[16384];
  int c = blockIdx.x, w = blockIdx.y, a = blockIdx.z;
  const int* keys = (a == 0) ? s0 : (a == 1) ? d0 : (a == 2) ? s1 : d1;
  int base = w * WIN0;
  int nb = w ? NB1 : WIN0;
  int nwords = nb >> 2;
  int t = threadIdx.x;
  for (int i = t; i < nwords; i += 256) bins[i] = 0;
  __syncthreads();
  int e0 = c * EC;
  for (int e = e0 + t; e < e0 + EC; e += 256) {
    int b = keys[e] - base;
    if ((unsigned)b < (unsigned)nb)
      atomicAdd(&bins[b >> 2], 1u << ((b & 3) * 8));
  }
  __syncthreads();
  unsigned* dst = partial + (size_t)(a * CH + c) * PROW + (w ? (WIN0 >> 2) : 0);
  for (int i = t; i < nwords; i += 256) dst[i] = bins[i];
}

// sum partials -> rsqrt-degrees; overwrite din rows with chunk prefixes.
__global__ __launch_bounds__(256) void deg_reduce_k(
    unsigned* __restrict__ partial, float* __restrict__ rs4, ushort* __restrict__ rsO01u,
    int* __restrict__ degIn0, int* __restrict__ degIn1) {
  int word = blockIdx.x * 256 + threadIdx.x;
  if (word >= PROW) return;
  int a = blockIdx.y;
  bool din = (a == 1) || (a == 3);
  unsigned r0 = 0, r1 = 0, r2 = 0, r3 = 0;
  unsigned* rowp = partial + (size_t)a * CH * PROW + word;
  for (int c = 0; c < CH; ++c) {
    unsigned* p = rowp + (size_t)c * PROW;
    unsigned v = *p;
    if (din) *p = r0 | (r1 << 8) | (r2 << 16) | (r3 << 24);
    r0 += v & 255u; r1 += (v >> 8) & 255u; r2 += (v >> 16) & 255u; r3 += (v >> 24) & 255u;
  }
  int b = word * 4;
  float4 r;
  r.x = rsqrtf((float)max(r0, 1u));
  r.y = rsqrtf((float)max(r1, 1u));
  r.z = rsqrtf((float)max(r2, 1u));
  r.w = rsqrtf((float)max(r3, 1u));
  *(float4*)&rs4[(size_t)a * N_NODES + b] = r;
  if (a == 0) {
    rsO01u[2 * (b + 0)] = f2bf(r.x); rsO01u[2 * (b + 1)] = f2bf(r.y);
    rsO01u[2 * (b + 2)] = f2bf(r.z); rsO01u[2 * (b + 3)] = f2bf(r.w);
  }
  if (a == 2) {
    rsO01u[2 * (b + 0) + 1] = f2bf(r.x); rsO01u[2 * (b + 1) + 1] = f2bf(r.y);
    rsO01u[2 * (b + 2) + 1] = f2bf(r.z); rsO01u[2 * (b + 3) + 1] = f2bf(r.w);
  }
  if (a == 1) { degIn0[b] = r0; degIn0[b + 1] = r1; degIn0[b + 2] = r2; degIn0[b + 3] = r3; }
  if (a == 3) { degIn1[b] = r0; degIn1[b + 1] = r1; degIn1[b + 2] = r2; degIn1[b + 3] = r3; }
}

// ---------------- 2-level exclusive scan (both graphs via blockIdx.y) ----------------
__global__ void scan_local_k(const int* __restrict__ cnt0, const int* __restrict__ cnt1,
                             int* __restrict__ out0, int* __restrict__ out1,
                             int* __restrict__ bsum) {
  __shared__ int lds[256];
  const int* cnt = blockIdx.y ? cnt1 : cnt0;
  int* out = blockIdx.y ? out1 : out0;
  int base = blockIdx.x * 2048;
  int t = threadIdx.x;
  int v[8];
  int s = 0;
#pragma unroll
  for (int j = 0; j < 8; ++j) {
    int idx = base + t * 8 + j;
    v[j] = (idx < N_NODES) ? cnt[idx] : 0;
    s += v[j];
  }
  lds[t] = s;
  __syncthreads();
  for (int off = 1; off < 256; off <<= 1) {
    int x = (t >= off) ? lds[t - off] : 0;
    __syncthreads();
    lds[t] += x;
    __syncthreads();
  }
  int excl = lds[t] - s;
  if (t == 255) bsum[blockIdx.y * 64 + blockIdx.x] = lds[255];
  int run = excl;
#pragma unroll
  for (int j = 0; j < 8; ++j) {
    int idx = base + t * 8 + j;
    if (idx < N_NODES) out[idx] = run;
    run += v[j];
  }
}

// apply block offsets; top-scan of raw block sums done in-kernel (wave 0)
__global__ void scan_apply_k(int* __restrict__ rp0, int* __restrict__ rp1,
                             const int* __restrict__ bsum) {
  __shared__ int ps[64];
  int* rp = blockIdx.y ? rp1 : rp0;
  const int* bs = bsum + blockIdx.y * 64;
  int t = threadIdx.x;
  if (t < 64) {
    int orig = bs[t];
    int v = orig;
#pragma unroll
    for (int off = 1; off < 64; off <<= 1) {
      int u = __shfl_up(v, off);
      if (t >= off) v += u;
    }
    ps[t] = v - orig;   // exclusive prefix
  }
  __syncthreads();
  int i = blockIdx.x * 256 + t;
  if (i < N_NODES) rp[i] += ps[i >> 11];
  if (i == 0) rp[N_NODES] = N_EDGES;
}

// ---------------- atomic-free CSR fill (two windows, both graphs via blockIdx.z) ----------------
__global__ __launch_bounds__(256) void csr_fill2_k(
    const int* __restrict__ src0, const int* __restrict__ dst0, const int* __restrict__ rp0g,
    int* __restrict__ csr0g,
    const int* __restrict__ src1, const int* __restrict__ dst1, const int* __restrict__ rp1g,
    int* __restrict__ csr1g, const unsigned* __restrict__ partial) {
  __shared__ unsigned bins[16384];
  int c = blockIdx.x, w = blockIdx.y, g = blockIdx.z;
  const int* src = g ? src1 : src0;
  const int* dst = g ? dst1 : dst0;
  const int* rp = g ? rp1g : rp0g;
  int* csr = g ? csr1g : csr0g;
  int aIdx = g ? 3 : 1;
  int base = w * WIN0;
  int nb = w ? NB1 : WIN0;
  int nwords = nb >> 2;
  const unsigned* sp = partial + (size_t)(aIdx * CH + c) * PROW + (w ? (WIN0 >> 2) : 0);
  int t = threadIdx.x;
  for (int i = t; i < nwords; i += 256) bins[i] = sp[i];
  __syncthreads();
  int e0 = c * EC;
  for (int e = e0 + t; e < e0 + EC; e += 256) {
    int d = dst[e];
    int b = d - base;
    if ((unsigned)b < (unsigned)nb) {
      int sh = (b & 3) * 8;
      unsigned old = atomicAdd(&bins[b >> 2], 1u << sh);
      int off = (old >> sh) & 255;
      csr[rp[d] + off] = src[e];
    }
  }
}

// ---------------- pack: feat fp32 -> bf16 rows (blocks 0..1023) + weights (blocks 1024..1055) ----------------
__global__ __launch_bounds__(256) void pack_all_k(
    const float* __restrict__ x, uint* __restrict__ y,
    const float* __restrict__ Wa, const float* __restrict__ Wb,
    const float* __restrict__ Wc, const float* __restrict__ Wd,
    ushort* __restrict__ pk) {
  int b = blockIdx.x;
  int t = threadIdx.x;
  if (b < 1024) {
    size_t total = (size_t)N_NODES * F / 8;
    for (size_t idx = b * 256 + t; idx < total; idx += (size_t)1024 * 256) {
      float4 v1 = ((const float4*)x)[idx * 2];
      float4 v2 = ((const float4*)x)[idx * 2 + 1];
      uint4 o;
      o.x = pk2(v1.x, v1.y);
      o.y = pk2(v1.z, v1.w);
      o.z = pk2(v2.x, v2.y);
      o.w = pk2(v2.z, v2.w);
      ((uint4*)y)[idx] = o;
    }
  } else {
    int bb = b - 1024;              // 0..31
    int m = bb >> 3;                // weight matrix 0..3
    int idx = (bb & 7) * 256 + t;   // 0..2047 = ks*512 + nt*64 + lane
    const float* W = (m == 0) ? Wa : (m == 1) ? Wb : (m == 2) ? Wc : Wd;
    int lane = idx & 63;
    int nt = (idx >> 6) & 7;
    int ks = idx >> 9;
    int j = (lane & 15) + nt * 16;
    int kb = (lane >> 4) * 8 + ks * 32;
    ushort v[8];
#pragma unroll
    for (int q = 0; q < 8; ++q) v[q] = f2bf(W[(size_t)(kb + q) * F + j]);
    *(uint4*)(pk + (size_t)m * 16384 + (size_t)idx * 8) = *(uint4*)v;
  }
}

// ---------------- stat reduction: GB per-block partials -> 64 -> 1 (no atomics) ----------------
__global__ void st_part_k(const float* __restrict__ stm, float* __restrict__ stp, int ncopies) {
  int b = blockIdx.x, t = threadIdx.x;
  int lo = b * 25, hi = min(ncopies, lo + 25);
  float s = 0.f;
  for (int k = lo; k < hi; ++k) s += stm[(size_t)k * 256 + t];
  stp[b * 256 + t] = s;
}

__global__ void st_final_k(const float* __restrict__ stp, float* __restrict__ st) {
  int t = threadIdx.x;
  float s = 0.f;
#pragma unroll
  for (int k = 0; k < 64; ++k) s += stp[k * 256 + t];
  st[t] = s;
}

// ---------------- quarter-wave gather helpers ----------------
__device__ __forceinline__ void acc8(uint4 v, float c, float* a) {
  a[0] = fmaf(bf_lo(v.x), c, a[0]); a[1] = fmaf(bf_hi(v.x), c, a[1]);
  a[2] = fmaf(bf_lo(v.y), c, a[2]); a[3] = fmaf(bf_hi(v.y), c, a[3]);
  a[4] = fmaf(bf_lo(v.z), c, a[4]); a[5] = fmaf(bf_hi(v.z), c, a[5]);
  a[6] = fmaf(bf_lo(v.w), c, a[6]); a[7] = fmaf(bf_hi(v.w), c, a[7]);
}

__device__ __forceinline__ void gather_run(const int* __restrict__ p, int n, float w,
                                           const float* __restrict__ rsO,
                                           const uint4* __restrict__ xr, int l, float* a) {
  int e = 0;
  for (; e + 3 < n; e += 4) {
    int s0 = p[e], s1 = p[e + 1], s2 = p[e + 2], s3 = p[e + 3];
    float c0 = w * rsO[s0], c1 = w * rsO[s1];
    float c2 = w * rsO[s2], c3 = w * rsO[s3];
    uint4 v0 = xr[(size_t)s0 * 16 + l];
    uint4 v1 = xr[(size_t)s1 * 16 + l];
    uint4 v2 = xr[(size_t)s2 * 16 + l];
    uint4 v3 = xr[(size_t)s3 * 16 + l];
    acc8(v0, c0, a); acc8(v1, c1, a); acc8(v2, c2, a); acc8(v3, c3, a);
  }
  for (; e < n; ++e) {
    int s = p[e];
    float c = w * rsO[s];
    uint4 v = xr[(size_t)s * 16 + l];
    acc8(v, c, a);
  }
}

// ---------------- dual-graph gather, 16-lane groups (uint4/lane), split per-graph loops ----------------
__global__ __launch_bounds__(256) void gather_dual_q_k(
    const uint* __restrict__ xbf, const float* __restrict__ attn,
    const float* __restrict__ rsO0f, const float* __restrict__ rsO1f,
    const float* __restrict__ rsI0, const int* __restrict__ rp0, const int* __restrict__ csr0,
    const float* __restrict__ rsI1, const int* __restrict__ rp1, const int* __restrict__ csr1,
    uint* __restrict__ outbf) {
  int node = blockIdx.x * 16 + (threadIdx.x >> 4);
  int l = threadIdx.x & 15;
  int b0 = rp0[node], n0 = rp0[node + 1] - b0;
  int b1 = rp1[node], n1 = rp1[node + 1] - b1;
  float w0 = attn[0] * rsI0[node];
  float w1 = attn[1] * rsI1[node];
  const uint4* xr = (const uint4*)xbf;
  float a[8] = {0.f, 0.f, 0.f, 0.f, 0.f, 0.f, 0.f, 0.f};
  gather_run(csr0 + b0, n0, w0, rsO0f, xr, l, a);
  gather_run(csr1 + b1, n1, w1, rsO1f, xr, l, a);
  uint4 o;
  o.x = pk2(a[0], a[1]); o.y = pk2(a[2], a[3]);
  o.z = pk2(a[4], a[5]); o.w = pk2(a[6], a[7]);
  ((uint4*)outbf)[(size_t)node * 16 + l] = o;
}

// ---------------- single-graph gather + inline BN/ReLU on sources, 16-lane groups ----------------
__device__ __forceinline__ void accbn(uint4 v, float c, const float* sc, const float* sh,
                                      float* a) {
  a[0] = fmaf(fmaxf(fmaf(bf_lo(v.x), sc[0], sh[0]), 0.f), c, a[0]);
  a[1] = fmaf(fmaxf(fmaf(bf_hi(v.x), sc[1], sh[1]), 0.f), c, a[1]);
  a[2] = fmaf(fmaxf(fmaf(bf_lo(v.y), sc[2], sh[2]), 0.f), c, a[2]);
  a[3] = fmaf(fmaxf(fmaf(bf_hi(v.y), sc[3], sh[3]), 0.f), c, a[3]);
  a[4] = fmaf(fmaxf(fmaf(bf_lo(v.z), sc[4], sh[4]), 0.f), c, a[4]);
  a[5] = fmaf(fmaxf(fmaf(bf_hi(v.z), sc[5], sh[5]), 0.f), c, a[5]);
  a[6] = fmaf(fmaxf(fmaf(bf_lo(v.w), sc[6], sh[6]), 0.f), c, a[6]);
  a[7] = fmaf(fmaxf(fmaf(bf_hi(v.w), sc[7], sh[7]), 0.f), c, a[7]);
}

__global__ __launch_bounds__(256) void gather_bn_q_k(
    const uint* __restrict__ xbf, const float* __restrict__ st,
    const float* __restrict__ gamma, const float* __restrict__ beta,
    const float* __restrict__ rsO,
    const float* __restrict__ rsI, const int* __restrict__ rp, const int* __restrict__ csr,
    uint* __restrict__ outbf) {
  int node = blockIdx.x * 16 + (threadIdx.x >> 4);
  int l = threadIdx.x & 15;
  float sc[8], sh[8];
#pragma unroll
  for (int j = 0; j < 8; ++j) {
    int c = 8 * l + j;
    float m = st[c] * (1.f / (float)N_NODES);
    float v = st[128 + c] * (1.f / (float)N_NODES) - m * m;
    float s = gamma[c] * rsqrtf(fmaxf(v, 0.f) + BN_EPS);
    sc[j] = s;
    sh[j] = beta[c] - m * s;
  }
  int b0 = rp[node], T = rp[node + 1] - b0;
  const int* p = csr + b0;
  const uint4* xr = (const uint4*)xbf;
  float a[8] = {0.f, 0.f, 0.f, 0.f, 0.f, 0.f, 0.f, 0.f};
  int e = 0;
  for (; e + 3 < T; e += 4) {   // 4-deep: 4 row-loads in flight per lane
    int s0 = p[e], s1 = p[e + 1], s2 = p[e + 2], s3 = p[e + 3];
    float c0 = rsO[s0], c1 = rsO[s1], c2 = rsO[s2], c3 = rsO[s3];
    uint4 v0 = xr[(size_t)s0 * 16 + l];
    uint4 v1 = xr[(size_t)s1 * 16 + l];
    uint4 v2 = xr[(size_t)s2 * 16 + l];
    uint4 v3 = xr[(size_t)s3 * 16 + l];
    accbn(v0, c0, sc, sh, a);
    accbn(v1, c1, sc, sh, a);
    accbn(v2, c2, sc, sh, a);
    accbn(v3, c3, sc, sh, a);
  }
  for (; e < T; ++e) {
    int s0 = p[e];
    float c0 = rsO[s0];
    uint4 v0 = xr[(size_t)s0 * 16 + l];
    accbn(v0, c0, sc, sh, a);
  }
  float sd = rsI[node];
  uint4 o;
  o.x = pk2(a[0] * sd, a[1] * sd); o.y = pk2(a[2] * sd, a[3] * sd);
  o.z = pk2(a[4] * sd, a[5] * sd); o.w = pk2(a[6] * sd, a[7] * sd);
  ((uint4*)outbf)[(size_t)node * 16 + l] = o;
}

// ---------------- gather 40 cols (bf16 input, 128B-aligned rows), accumulate into out ----------------
__global__ void gather40_add_k(const uint* __restrict__ x2bf, const float* __restrict__ rsI,
                               const int* __restrict__ rp, const int* __restrict__ csr,
                               float* __restrict__ out) {
  int node = (blockIdx.x * 256 + threadIdx.x) >> 5;
  int lane = threadIdx.x & 31;
  if (node >= N_NODES || lane >= 20) return;
  float l = 0.f, h = 0.f;
  int e = rp[node], end = rp[node + 1];
  for (; e + 3 < end; e += 4) {
    int sA = csr[e], sB = csr[e + 1], sC = csr[e + 2], sD = csr[e + 3];
    uint vA = x2bf[(size_t)sA * X2S + lane];
    uint vB = x2bf[(size_t)sB * X2S + lane];
    uint vC = x2bf[(size_t)sC * X2S + lane];
    uint vD = x2bf[(size_t)sD * X2S + lane];
    l += (bf_lo(vA) + bf_lo(vB)) + (bf_lo(vC) + bf_lo(vD));
    h += (bf_hi(vA) + bf_hi(vB)) + (bf_hi(vC) + bf_hi(vD));
  }
  for (; e < end; ++e) {
    uint vA = x2bf[(size_t)csr[e] * X2S + lane];
    l += bf_lo(vA);
    h += bf_hi(vA);
  }
  float sd = rsI[node];
  float2 p = *(float2*)(out + (size_t)node * NC + lane * 2);
  *(float2*)(out + (size_t)node * NC + lane * 2) = make_float2(p.x + l * sd, p.y + h * sd);
}

// ---------------- MFMA dual GEMM: direct A loads, LDS C epilogue, no global atomics ----------------
__global__ __launch_bounds__(256) void gemm_mfma_k(
    const ushort* __restrict__ A1, const ushort* __restrict__ A2,
    const ushort* __restrict__ pkA, const ushort* __restrict__ pkB,
    float* __restrict__ stm, ushort* __restrict__ Cb) {
  __shared__ uint Cl[64 * CSU];   // 17.4 KB
  __shared__ float sst[256];
  int t = threadIdx.x;
  sst[t] = 0.f;
  __syncthreads();
  int wave = t >> 6, lane = t & 63;
  int kgrp = lane >> 4, lrow = lane & 15;
  int arow = blockIdx.x * 64 + wave * 16 + lrow;
  bool rok = arow < N_NODES;
  const vbf8* a1p = (const vbf8*)(A1 + (size_t)(rok ? arow : 0) * F);
  const vbf8* a2p = (const vbf8*)(A2 + (size_t)(rok ? arow : 0) * F);
  const vbf8* wap = (const vbf8*)pkA + lane;
  const vbf8* wbp = (const vbf8*)pkB + lane;
  vbf8 zero = {0, 0, 0, 0, 0, 0, 0, 0};
  vf4 acc[8];
#pragma unroll
  for (int i = 0; i < 8; ++i) acc[i] = (vf4){0.f, 0.f, 0.f, 0.f};
#pragma unroll
  for (int ks = 0; ks < 4; ++ks) {
    vbf8 a1 = rok ? a1p[ks * 4 + kgrp] : zero;
    vbf8 a2 = rok ? a2p[ks * 4 + kgrp] : zero;
#pragma unroll
    for (int nt = 0; nt < 8; ++nt)
      acc[nt] = __builtin_amdgcn_mfma_f32_16x16x32_bf16(a1, wap[(ks * 8 + nt) * 64], acc[nt], 0, 0, 0);
#pragma unroll
    for (int nt = 0; nt < 8; ++nt)
      acc[nt] = __builtin_amdgcn_mfma_f32_16x16x32_bf16(a2, wbp[(ks * 8 + nt) * 64], acc[nt], 0, 0, 0);
  }
  // epilogue: pair-pack C into LDS, block-wide stats into LDS
  int row_l = wave * 16 + kgrp * 4;
#pragma unroll
  for (int nt = 0; nt < 8; ++nt) {
#pragma unroll
    for (int r = 0; r < 4; ++r) {
      float w = acc[nt][r];
      float o = __shfl_xor(w, 1);
      if ((lrow & 1) == 0) Cl[(row_l + r) * CSU + nt * 8 + (lrow >> 1)] = pk2(w, o);
    }
  }
#pragma unroll
  for (int nt = 0; nt < 8; ++nt) {
    float s = acc[nt][0] + acc[nt][1] + acc[nt][2] + acc[nt][3];
    float q = acc[nt][0] * acc[nt][0] + acc[nt][1] * acc[nt][1] +
              acc[nt][2] * acc[nt][2] + acc[nt][3] * acc[nt][3];
    s += __shfl_xor(s, 16); q += __shfl_xor(q, 16);
    s += __shfl_xor(s, 32); q += __shfl_xor(q, 32);
    if (lane < 16) {
      atomicAdd(&sst[nt * 16 + lane], s);
      atomicAdd(&sst[128 + nt * 16 + lane], q);
    }
  }
  __syncthreads();
  // coalesced C store: 64 rows x 64 uints = 1024 uint4
#pragma unroll
  for (int i = 0; i < 4; ++i) {
    int u = t + 256 * i;
    int row = u >> 4, seg = (u & 15) * 4;
    int grow = blockIdx.x * 64 + row;
    if (grow < N_NODES)
      *(uint4*)((uint*)Cb + (size_t)grow * 64 + seg) = *(uint4*)&Cl[row * CSU + seg];
  }
  // per-block stat partials: plain coalesced store (no device atomics)
  stm[(size_t)blockIdx.x * 256 + t] = sst[t];
}

// ---------------- MFMA dual GEMM, A2 = relu(bn(raw)) at fragment load (in-place safe) ----------------
__global__ __launch_bounds__(256) void gemm_mfma_bn_k(
    const ushort* __restrict__ A1, const ushort* __restrict__ A2,
    const float* __restrict__ stin, const float* __restrict__ gamma,
    const float* __restrict__ beta,
    const ushort* __restrict__ pkA, const ushort* __restrict__ pkB,
    float* __restrict__ stm, ushort* __restrict__ Cb) {
  __shared__ uint Cl[64 * CSU];
  __shared__ float sst[256];
  __shared__ float scl[128], shl[128];
  int t = threadIdx.x;
  sst[t] = 0.f;
  if (t < 128) {
    float m = stin[t] * (1.f / (float)N_NODES);
    float v = stin[128 + t] * (1.f / (float)N_NODES) - m * m;
    float s = gamma[t] * rsqrtf(fmaxf(v, 0.f) + BN_EPS);
    scl[t] = s;
    shl[t] = beta[t] - m * s;
  }
  __syncthreads();
  int wave = t >> 6, lane = t & 63;
  int kgrp = lane >> 4, lrow = lane & 15;
  int arow = blockIdx.x * 64 + wave * 16 + lrow;
  bool rok = arow < N_NODES;
  const vbf8* a1p = (const vbf8*)(A1 + (size_t)(rok ? arow : 0) * F);
  const vbf8* a2p = (const vbf8*)(A2 + (size_t)(rok ? arow : 0) * F);
  const vbf8* wap = (const vbf8*)pkA + lane;
  const vbf8* wbp = (const vbf8*)pkB + lane;
  vbf8 zero = {0, 0, 0, 0, 0, 0, 0, 0};
  vf4 acc[8];
#pragma unroll
  for (int i = 0; i < 8; ++i) acc[i] = (vf4){0.f, 0.f, 0.f, 0.f};
#pragma unroll
  for (int ks = 0; ks < 4; ++ks) {
    vbf8 a1 = rok ? a1p[ks * 4 + kgrp] : zero;
    vbf8 a2 = zero;
    if (rok) {
      vbf8 a2r = a2p[ks * 4 + kgrp];
      const float* scp = &scl[ks * 32 + kgrp * 8];
      const float* shp = &shl[ks * 32 + kgrp * 8];
      ushort o[8];
#pragma unroll
      for (int q = 0; q < 8; ++q) {
        float f = __uint_as_float(((uint)(ushort)a2r[q]) << 16);
        f = fmaxf(fmaf(f, scp[q], shp[q]), 0.f);
        o[q] = f2bf(f);
      }
      a2 = *(vbf8*)o;
    }
#pragma unroll
    for (int nt = 0; nt < 8; ++nt)
      acc[nt] = __builtin_amdgcn_mfma_f32_16x16x32_bf16(a1, wap[(ks * 8 + nt) * 64], acc[nt], 0, 0, 0);
#pragma unroll
    for (int nt = 0; nt < 8; ++nt)
      acc[nt] = __builtin_amdgcn_mfma_f32_16x16x32_bf16(a2, wbp[(ks * 8 + nt) * 64], acc[nt], 0, 0, 0);
  }
  int row_l = wave * 16 + kgrp * 4;
#pragma unroll
  for (int nt = 0; nt < 8; ++nt) {
#pragma unroll
    for (int r = 0; r < 4; ++r) {
      float w = acc[nt][r];
      float o = __shfl_xor(w, 1);
      if ((lrow & 1) == 0) Cl[(row_l + r) * CSU + nt * 8 + (lrow >> 1)] = pk2(w, o);
    }
  }
#pragma unroll
  for (int nt = 0; nt < 8; ++nt) {
    float s = acc[nt][0] + acc[nt][1] + acc[nt][2] + acc[nt][3];
    float q = acc[nt][0] * acc[nt][0] + acc[nt][1] * acc[nt][1] +
              acc[nt][2] * acc[nt][2] + acc[nt][3] * acc[nt][3];
    s += __shfl_xor(s, 16); q += __shfl_xor(q, 16);
    s += __shfl_xor(s, 32); q += __shfl_xor(q, 32);
    if (lane < 16) {
      atomicAdd(&sst[nt * 16 + lane], s);
      atomicAdd(&sst[128 + nt * 16 + lane], q);
    }
  }
  __syncthreads();   // all A2 reads complete before any store (in-place safe)
#pragma unroll
  for (int i = 0; i < 4; ++i) {
    int u = t + 256 * i;
    int row = u >> 4, seg = (u & 15) * 4;
    int grow = blockIdx.x * 64 + row;
    if (grow < N_NODES)
      *(uint4*)((uint*)Cb + (size_t)grow * 64 + seg) = *(uint4*)&Cl[row * CSU + seg];
  }
  stm[(size_t)blockIdx.x * 256 + t] = sst[t];
}

// ---------------- layer-2 dual GEMM (inline BN from raw stats) ----------------
__global__ __launch_bounds__(256) void gemm40_dual_k(
    const uint* __restrict__ h1b, const float* __restrict__ st,
    const float* __restrict__ gamma, const float* __restrict__ beta,
    const float* __restrict__ W2, const float* __restrict__ L2, const float* __restrict__ bias,
    const float* __restrict__ rsO, uint* __restrict__ x2bf, float* __restrict__ outp) {
  __shared__ float Alds[25 * 128];
  __shared__ float Wl[128 * NC];
  __shared__ float Ll[128 * NC];
  __shared__ float scl[128], shl[128];
  int t = threadIdx.x;
  int r0 = blockIdx.x * 25;
  if (t < 128) {
    float m = st[t] / (float)N_NODES;
    float v = st[128 + t] / (float)N_NODES - m * m;
    float s = gamma[t] * rsqrtf(fmaxf(v, 0.f) + BN_EPS);
    scl[t] = s;
    shl[t] = beta[t] - m * s;
  }
  __syncthreads();
#pragma unroll
  for (int p = 0; p < 4; ++p) {
    int flat = t * 4 + p * 1024;
    if (flat < 25 * 128) {
      int lrr = flat >> 7, k = flat & 127;
      int row = r0 + lrr;
      float4 v = make_float4(0.f, 0.f, 0.f, 0.f);
      if (row < N_NODES) {
        uint2 u = *(const uint2*)(h1b + (size_t)row * 64 + (k >> 1));
        v = make_float4(bf_lo(u.x), bf_hi(u.x), bf_lo(u.y), bf_hi(u.y));
      }
      float4 scv = *(float4*)&scl[k];
      float4 shv = *(float4*)&shl[k];
      v.x = fmaxf(fmaf(v.x, scv.x, shv.x), 0.f);
      v.y = fmaxf(fmaf(v.y, scv.y, shv.y), 0.f);
      v.z = fmaxf(fmaf(v.z, scv.z, shv.z), 0.f);
      v.w = fmaxf(fmaf(v.w, scv.w, shv.w), 0.f);
      *(float4*)&Alds[flat] = v;
    }
  }
#pragma unroll
  for (int p = 0; p < 5; ++p) {
    int flat = t * 4 + p * 1024;
    if (flat < 128 * NC) {
      *(float4*)&Wl[flat] = *(const float4*)(W2 + flat);
      *(float4*)&Ll[flat] = *(const float4*)(L2 + flat);
    }
  }
  __syncthreads();
  if (t < 250) {
    int lrr = t / 10, cg = t % 10;
    float w0 = 0.f, w1 = 0.f, w2 = 0.f, w3 = 0.f;
    float l0 = 0.f, l1 = 0.f, l2 = 0.f, l3 = 0.f;
#pragma unroll 8
    for (int k = 0; k < 128; ++k) {
      float a = Alds[lrr * 128 + k];
      float4 w = *(float4*)&Wl[k * NC + cg * 4];
      float4 l = *(float4*)&Ll[k * NC + cg * 4];
      w0 = fmaf(a, w.x, w0); w1 = fmaf(a, w.y, w1);
      w2 = fmaf(a, w.z, w2); w3 = fmaf(a, w.w, w3);
      l0 = fmaf(a, l.x, l0); l1 = fmaf(a, l.y, l1);
      l2 = fmaf(a, l.z, l2); l3 = fmaf(a, l.w, l3);
    }
    int row = r0 + lrr;
    if (row < N_NODES) {
      float s = rsO[row];
      uint2 xo = make_uint2(pk2(w0 * s, w1 * s), pk2(w2 * s, w3 * s));
      *(uint2*)(x2bf + (size_t)row * X2S + cg * 2) = xo;
      float4 bv = *(const float4*)(bias + cg * 4);
      float4 oo = make_float4(l0 + bv.x, l1 + bv.y, l2 + bv.z, l3 + bv.w);
      *(float4*)(outp + (size_t)row * NC + cg * 4) = oo;
    }
  }
}

extern "C" void kernel_launch(void* const* d_in, const int* in_sizes, int n_in,
                              void* d_out, int out_size, void* d_ws, size_t ws_size,
                              hipStream_t stream) {
  const float* feat = (const float*)d_in[0];
  const int* src0 = (const int*)d_in[1];
  const int* dst0 = (const int*)d_in[2];
  const int* src1 = (const int*)d_in[3];
  const int* dst1 = (const int*)d_in[4];
  const float* attn = (const float*)d_in[5];
  const float* W0 = (const float*)d_in[6];
  const float* W1 = (const float*)d_in[7];
  const float* W2 = (const float*)d_in[8];
  const float* b2 = (const float*)d_in[9];
  const float* L0 = (const float*)d_in[10];
  const float* L1 = (const float*)d_in[11];
  const float* L2 = (const float*)d_in[12];
  const float* gamma0 = (const float*)d_in[13];
  const float* beta0 = (const float*)d_in[14];
  const float* gamma1 = (const float*)d_in[15];
  const float* beta1 = (const float*)d_in[16];
  float* out = (float*)d_out;

  char* base = (char*)d_ws;
  size_t off = 0;
  auto alloc = [&](size_t bytes) -> void* {
    void* p = base + off;
    off += (bytes + 255) & ~(size_t)255;
    return p;
  };
  unsigned* partial = (unsigned*)alloc((size_t)4 * CH * PROW * 4);  // 25.6 MB
  float* rs4 = (float*)alloc(4 * (size_t)N_NODES * 4);
  uint* rsO01 = (uint*)alloc((size_t)N_NODES * 4);
  int* degIn0 = (int*)alloc(N_NODES * 4);
  int* degIn1 = (int*)alloc(N_NODES * 4);
  int* rp0 = (int*)alloc((N_NODES + 1) * 4);
  int* rp1 = (int*)alloc((N_NODES + 1) * 4);
  int* bsum = (int*)alloc(128 * 4);
  int* csr0 = (int*)alloc((size_t)N_EDGES * 4);
  int* csr1 = (int*)alloc((size_t)N_EDGES * 4);
  float* stm0 = (float*)alloc((size_t)GB * 256 * 4);       // 1.6 MB per-block stat partials
  float* stm1 = (float*)alloc((size_t)GB * 256 * 4);
  float* stp = (float*)alloc((size_t)64 * 256 * 4);        // 64 KB tree stage
  float* st0 = (float*)alloc(256 * 4);
  float* st1 = (float*)alloc(256 * 4);
  ushort* wpk = (ushort*)alloc((size_t)4 * 16384 * 2);     // 128 KB packed weights
  uint* featbf = (uint*)alloc((size_t)N_NODES * 64 * 4);   // 25.6 MB
  uint* aggbf = (uint*)alloc((size_t)N_NODES * 64 * 4);    // 25.6 MB
  uint* hrow = (uint*)alloc((size_t)N_NODES * 64 * 4);     // 25.6 MB (h0 then h1, bf16)
  uint* g1buf = (uint*)alloc((size_t)N_NODES * 64 * 4);    // 25.6 MB
  if (off > ws_size) return;

  // buffer reuse (sequential stream makes these safe)
  uint* x2bf = featbf;   // after gemm0 consumed featbf (needs 12.8 MB of its 25.6 MB)

  float* rs_out0 = rs4;                 // out-deg graph0 (fp32)
  float* rs_in0 = rs4 + N_NODES;        // in-deg graph0
  float* rs_out1 = rs4 + 2 * N_NODES;   // out-deg graph1
  float* rs_in1 = rs4 + 3 * N_NODES;    // in-deg graph1

  // graph prep
  hist_count_k<<<dim3(CH, 2, 4), 256, 0, stream>>>(src0, dst0, src1, dst1, partial);
  deg_reduce_k<<<dim3((PROW + 255) / 256, 4), 256, 0, stream>>>(
      partial, rs4, (ushort*)rsO01, degIn0, degIn1);
  const int SCB = (N_NODES + 2047) / 2048;
  scan_local_k<<<dim3(SCB, 2), 256, 0, stream>>>(degIn0, degIn1, rp0, rp1, bsum);
  scan_apply_k<<<dim3((N_NODES + 255) / 256, 2), 256, 0, stream>>>(rp0, rp1, bsum);
  csr_fill2_k<<<dim3(CH, 2, 2), 256, 0, stream>>>(src0, dst0, rp0, csr0,
                                                  src1, dst1, rp1, csr1, partial);

  // packs (feat + weights in one launch)
  pack_all_k<<<1056, 256, 0, stream>>>(feat, featbf, W0, L0, W1, L1, wpk);

  // layer 0
  gather_dual_q_k<<<N_NODES / 16, 256, 0, stream>>>(featbf, attn, rs_out0, rs_out1,
                                                    rs_in0, rp0, csr0,
                                                    rs_in1, rp1, csr1, aggbf);
  gemm_mfma_k<<<GB, 256, 0, stream>>>((ushort*)aggbf, (ushort*)featbf, wpk, wpk + 16384,
                                      stm0, (ushort*)hrow);
  st_part_k<<<64, 256, 0, stream>>>(stm0, stp, GB);
  st_final_k<<<1, 256, 0, stream>>>(stp, st0);

  // layer 1 (BN+ReLU of h0 fused into gather and into gemm A2 path)
  gather_bn_q_k<<<N_NODES / 16, 256, 0, stream>>>(hrow, st0, gamma0, beta0, rs_out0,
                                                  rs_in0, rp0, csr0, g1buf);
  gemm_mfma_bn_k<<<GB, 256, 0, stream>>>((ushort*)g1buf, (ushort*)hrow, st0, gamma0, beta0,
                                         wpk + 2 * 16384, wpk + 3 * 16384, stm1, (ushort*)hrow);
  st_part_k<<<64, 256, 0, stream>>>(stm1, stp, GB);
  st_final_k<<<1, 256, 0, stream>>>(stp, st1);

  // layer 2
  gemm40_dual_k<<<(N_NODES + 24) / 25, 256, 0, stream>>>(hrow, st1, gamma1, beta1, W2, L2, b2,
                                                         rs_out0, x2bf, out);
  gather40_add_k<<<(N_NODES * 32 + 255) / 256, 256, 0, stream>>>(x2bf, rs_in0, rp0, csr0, out);
}